// Round 1
// baseline (357.403 us; speedup 1.0000x reference)
//
#include <hip/hip_runtime.h>
#include <hip/hip_bf16.h>

typedef __attribute__((ext_vector_type(8))) short short8;
typedef __attribute__((ext_vector_type(4))) short short4v;
typedef __attribute__((ext_vector_type(4))) float f32x4;

#define BATCH 32
#define NCH   256
#define HW    56
#define NPIX  3136
#define XT_R  58

// Xt layout: [b][s8][hh58][ww58][fi32] bf16  (fi-chunk-major, halo built in)
#define XT_SLAB   (XT_R * XT_R * 32 * 2)            // 215,296 B per (b,s)
#define XT_BYTES  ((size_t)BATCH * 8 * XT_SLAB)     // 55,115,776
// Wm layout: [b][s8][tap9][fo256][fi32] bf16
#define WM_TAP    (256 * 32 * 2)                    // 16,384 B
#define WM_SLAB   (9 * WM_TAP)                      // 147,456 B per (b,s)
#define WM_B      (8 * WM_SLAB)                     // 1,179,648 B per b
#define WM_BYTES  ((size_t)BATCH * WM_B)            // 37,748,736
#define WS_NEEDED (XT_BYTES + WM_BYTES)             // ~92.9 MB (Xt first: B-stage overrun pads into Wm)

#define GLL16(g, l) __builtin_amdgcn_global_load_lds( \
    (const __attribute__((address_space(1))) void*)(g), \
    (__attribute__((address_space(3))) void*)(l), 16, 0, 0)

static __device__ __forceinline__ short f2bf(float f) {
    union { __hip_bfloat16 h; short s; } u;
    u.h = __float2bfloat16(f);
    return u.s;
}

// ---------------- halo zero: only the 58x58 border of each (b,s) slab --------------
__global__ __launch_bounds__(256) void halo_zero(char* xtb) {
    const int t = threadIdx.x;
    unsigned* p = (unsigned*)(xtb + (size_t)blockIdx.x * XT_SLAB);
    for (int i = t; i < 928; i += 256) { p[i] = 0u; p[57 * 928 + i] = 0u; }  // rows 0, 57
    for (int j = t; j < 896; j += 256) {                                     // cols 0, 57
        int r = (j >> 4) + 1, c = j & 15;
        p[r * 928 + c] = 0u;
        p[r * 928 + 912 + c] = 0u;
    }
}

// ---------------- wm prep: [b][s][tap][fo][fi32] = bf16(weight*m) ------------------
// block = (b, fo); float4 reads, LDS round-trip, 4B coalesced writes
__global__ __launch_bounds__(256) void wm_prep(const float* __restrict__ w,
                                               const float* __restrict__ m,
                                               char* __restrict__ wmb) {
    __shared__ short prod[2304];   // [fi][tap]
    const int b = blockIdx.x >> 8, fo = blockIdx.x & 255, t = threadIdx.x;
    const float4* m4 = (const float4*)(m + ((size_t)(b * NCH + fo)) * 2304);
    const float4* w4 = (const float4*)(w + (size_t)fo * 2304);
#pragma unroll
    for (int i = 0; i < 3; ++i) {
        int idx = i * 256 + t;
        if (idx < 576) {
            float4 a = w4[idx], mm = m4[idx];
            short4v s;
            s.x = f2bf(a.x * mm.x); s.y = f2bf(a.y * mm.y);
            s.z = f2bf(a.z * mm.z); s.w = f2bf(a.w * mm.w);
            ((short4v*)prod)[idx] = s;
        }
    }
    __syncthreads();
    char* ob = wmb + (size_t)b * WM_B + fo * 64;
#pragma unroll
    for (int i = 0; i < 5; ++i) {
        int q = i * 256 + t;
        if (q < 1152) {
            int o = q * 2;
            int s = o / 288, r = o - s * 288;
            int tap = r >> 5, fi = r & 31;
            unsigned lo = (unsigned short)prod[(s * 32 + fi) * 9 + tap];
            unsigned hi = (unsigned short)prod[(s * 32 + fi + 1) * 9 + tap];
            *(unsigned*)(ob + s * WM_SLAB + tap * WM_TAP + fi * 2) = lo | (hi << 16);
        }
    }
}

// ---------------- xt prep: [b][s][hh][ww][fi32] interior (halo pre-zeroed) ---------
// block = (b, h): transpose one image row across all 256 fi
__global__ __launch_bounds__(256) void xt_prep(const float* __restrict__ x,
                                               char* __restrict__ xtb) {
    __shared__ short xl[NCH * HW];   // [fi][w], 57,344 B
    const int blk = blockIdx.x;
    const int b = blk / HW, h = blk % HW, t = threadIdx.x;
    const float4* x4 = (const float4*)(x + (size_t)b * NCH * NPIX);
    const int rowb = h * 14;
#pragma unroll
    for (int i = 0; i < 14; ++i) {             // 3584 float4 = 256 fi x 14
        int c = i * 256 + t;
        int fi = c / 14, j = c - fi * 14;
        float4 v = x4[(size_t)fi * 784 + rowb + j];
        short4v s;
        s.x = f2bf(v.x); s.y = f2bf(v.y); s.z = f2bf(v.z); s.w = f2bf(v.w);
        ((short4v*)xl)[fi * 14 + j] = s;
    }
    __syncthreads();
    char* ob = xtb + (size_t)(b * 8) * XT_SLAB + (h + 1) * 3712 + 64;
#pragma unroll
    for (int i = 0; i < 28; ++i) {             // 7168 fi-pairs = 8s x 56ww x 16
        int q = i * 256 + t;
        int s = q / 896, rr = q - s * 896;
        int ww = rr >> 4, fp = rr & 15;
        int fi = s * 32 + 2 * fp;
        unsigned lo = (unsigned short)xl[fi * HW + ww];
        unsigned hi = (unsigned short)xl[(fi + 1) * HW + ww];
        *(unsigned*)(ob + s * XT_SLAB + ww * 64 + fp * 4) = lo | (hi << 16);
    }
}

// ---------------- main GEMM: block = 64 fo x 448 px (8 rows), K-loop = 8 fi-chunks -
// per fi-step: stage A(64x9x32) + B(10x58x32 halo), then 9 taps x 252 MFMA/wave
__global__ __launch_bounds__(256, 2) void gemm_dwa(const char* __restrict__ xtb,
                                                   const char* __restrict__ wmb,
                                                   const float* __restrict__ bias,
                                                   float* __restrict__ out) {
    __shared__ short Alds[2304 * 8];   // 36,864 B: [tap][fo64][fi32]
    __shared__ short Blds[2560 * 8];   // 40,960 B: [px 10x58][fi32] (+pad for uniform staging)

    const int tid = threadIdx.x, lane = tid & 63, wv = tid >> 6;
    const int ln = lane & 15, kg = lane >> 4;

    // XCD swizzle: pin each sample's working set to one XCD's L2 (perf heuristic only)
    const int blk = blockIdx.x;              // 896 = 8 xcd * 112
    const int xcd = blk & 7, slot = blk >> 3;
    const int b = xcd + 8 * (slot / 28);
    const int inner = slot % 28;
    const int ft = inner / 7, rt = inner % 7;
    const int fo0 = ft * 64, h0 = rt * 8;

    // per-lane B fragment pixel bases (halo-tile linear index, row stride 58)
    int pbase[7];
#pragma unroll
    for (int ni = 0; ni < 7; ++ni) {
        int p = wv * 112 + ni * 16 + ln;
        int hh = p / 56;
        pbase[ni] = hh * XT_R + (p - hh * 56);
    }

    const char* Ag = wmb + (size_t)b * WM_B + fo0 * 64;
    const char* Bg = xtb + (size_t)(b * 8) * XT_SLAB + h0 * 3712;

    f32x4 acc[4][7];
#pragma unroll
    for (int mi = 0; mi < 4; ++mi)
#pragma unroll
        for (int ni = 0; ni < 7; ++ni) acc[mi][ni] = (f32x4)0.0f;

    for (int s = 0; s < 8; ++s) {
        const char* ag = Ag + s * WM_SLAB;
        const char* bg = Bg + (size_t)s * XT_SLAB;

        __syncthreads();   // prior frag reads done
#pragma unroll
        for (int i = 0; i < 9; ++i) {          // A: 2304 chunks of 16B
            int c = i * 256 + tid;
            GLL16(ag + (c >> 8) * WM_TAP + (c & 255) * 16,
                  (char*)Alds + (i * 256 + wv * 64) * 16);
        }
#pragma unroll
        for (int i = 0; i < 10; ++i) {         // B: 2320 real + 240 pad chunks
            int c = i * 256 + tid;
            GLL16(bg + c * 16,
                  (char*)Blds + (i * 256 + wv * 64) * 16);
        }
        __syncthreads();   // staging drained

#pragma unroll
        for (int tap = 0; tap < 9; ++tap) {
            const int kh = tap / 3, kw = tap - kh * 3;
            const int shift = (kh * XT_R + kw) * 64;
            short8 af[4];
#pragma unroll
            for (int mi = 0; mi < 4; ++mi)
                af[mi] = *(const short8*)((const char*)Alds + tap * 4096 + (mi * 16 + ln) * 64 + kg * 16);
            short8 bf[7];
#pragma unroll
            for (int ni = 0; ni < 7; ++ni)
                bf[ni] = *(const short8*)((const char*)Blds + pbase[ni] * 64 + shift + kg * 16);
#pragma unroll
            for (int mi = 0; mi < 4; ++mi)
#pragma unroll
                for (int ni = 0; ni < 7; ++ni)
                    acc[mi][ni] = __builtin_amdgcn_mfma_f32_16x16x32_bf16(
                        af[mi], bf[ni], acc[mi][ni], 0, 0, 0);
        }
    }

    // epilogue: C row(fo) = (lane>>4)*4 + r, col(px) = lane&15 (round-2-verified)
#pragma unroll
    for (int mi = 0; mi < 4; ++mi) {
#pragma unroll
        for (int r = 0; r < 4; ++r) {
            const int row = fo0 + mi * 16 + kg * 4 + r;
            const float bv = bias[row];
            float* op = out + ((size_t)(b * NCH + row)) * NPIX + rt * 448 + wv * 112;
#pragma unroll
            for (int ni = 0; ni < 7; ++ni)
                op[ni * 16 + ln] = acc[mi][ni][r] + bv;
        }
    }
}

// ---------------- round-1 fp32 fallback (ws too small) -----------------------------
#define XS_W 60
#define XS_H 58
#define NGROUPS (NPIX / 4)
__global__ __launch_bounds__(256) void conv_dwa_fp32(
    const float* __restrict__ x, const float* __restrict__ m,
    const float* __restrict__ weight, const float* __restrict__ bias,
    float* __restrict__ out) {
    __shared__ float xs[XS_H * XS_W];
    const int tid = threadIdx.x, blk = blockIdx.x;
    const int b = blk >> 8, fo = blk & 255;
    const float* xb = x + (size_t)b * NCH * NPIX;
    const float* mb = m + ((size_t)b * NCH + fo) * (NCH * 9);
    const float* wb = weight + (size_t)fo * (NCH * 9);
    float acc[4][4];
#pragma unroll
    for (int g = 0; g < 4; ++g)
#pragma unroll
        for (int i = 0; i < 4; ++i) acc[g][i] = 0.0f;
    int rowbase[4];
#pragma unroll
    for (int g = 0; g < 4; ++g) {
        int p0 = (tid + g * 256) * 4;
        int gh = p0 / HW;
        rowbase[g] = gh * XS_W + (p0 - gh * HW);
    }
    for (int fi = 0; fi < NCH; ++fi) {
        const float* xp = xb + (size_t)fi * NPIX;
        __syncthreads();
        for (int idx = tid; idx < XS_H * 58; idx += 256) {
            int hh = idx / 58, ww = idx - hh * 58;
            int h = hh - 1, w = ww - 1;
            float v = 0.0f;
            if ((unsigned)h < HW && (unsigned)w < HW) v = xp[h * HW + w];
            xs[hh * XS_W + ww] = v;
        }
        float wm9[9];
#pragma unroll
        for (int j = 0; j < 9; ++j) wm9[j] = wb[fi * 9 + j] * mb[fi * 9 + j];
        __syncthreads();
#pragma unroll
        for (int g = 0; g < 4; ++g) {
            if (tid + g * 256 >= NGROUPS) break;
            const float* row0 = &xs[rowbase[g]];
#pragma unroll
            for (int kh = 0; kh < 3; ++kh) {
                const float* r = row0 + kh * XS_W;
                float s0 = r[0], s1 = r[1], s2 = r[2], s3 = r[3], s4 = r[4], s5 = r[5];
                const float w0 = wm9[3 * kh], w1 = wm9[3 * kh + 1], w2 = wm9[3 * kh + 2];
                acc[g][0] = fmaf(s2, w2, fmaf(s1, w1, fmaf(s0, w0, acc[g][0])));
                acc[g][1] = fmaf(s3, w2, fmaf(s2, w1, fmaf(s1, w0, acc[g][1])));
                acc[g][2] = fmaf(s4, w2, fmaf(s3, w1, fmaf(s2, w0, acc[g][2])));
                acc[g][3] = fmaf(s5, w2, fmaf(s4, w1, fmaf(s3, w0, acc[g][3])));
            }
        }
    }
    const float bv = bias[fo];
    float* ob = out + ((size_t)b * NCH + fo) * NPIX;
#pragma unroll
    for (int g = 0; g < 4; ++g) {
        int gi = tid + g * 256;
        if (gi >= NGROUPS) break;
        float4 v;
        v.x = acc[g][0] + bv; v.y = acc[g][1] + bv;
        v.z = acc[g][2] + bv; v.w = acc[g][3] + bv;
        *(float4*)(ob + gi * 4) = v;
    }
}

extern "C" void kernel_launch(void* const* d_in, const int* in_sizes, int n_in,
                              void* d_out, int out_size, void* d_ws, size_t ws_size,
                              hipStream_t stream) {
    const float* x      = (const float*)d_in[0];
    const float* m      = (const float*)d_in[1];
    const float* weight = (const float*)d_in[2];
    const float* bias   = (const float*)d_in[3];
    float* out          = (float*)d_out;

    if (ws_size < WS_NEEDED) {   // constant across calls -> graph-safe
        conv_dwa_fp32<<<dim3(BATCH * NCH), dim3(256), 0, stream>>>(x, m, weight, bias, out);
        return;
    }

    char* xtb = (char*)d_ws;            // Xt first: gemm B-stage pad overruns into Wm (in-bounds)
    char* wmb = xtb + XT_BYTES;

    halo_zero<<<dim3(BATCH * 8), dim3(256), 0, stream>>>(xtb);
    wm_prep<<<dim3(BATCH * NCH), dim3(256), 0, stream>>>(weight, m, wmb);
    xt_prep<<<dim3(BATCH * HW), dim3(256), 0, stream>>>(x, xtb);
    gemm_dwa<<<dim3(896), dim3(256), 0, stream>>>(xtb, wmb, bias, out);
}

// Round 4
// 338.036 us; speedup vs baseline: 1.0573x; 1.0573x over previous
//
#include <hip/hip_runtime.h>
#include <hip/hip_bf16.h>

typedef __attribute__((ext_vector_type(8))) short short8;
typedef __attribute__((ext_vector_type(4))) short short4v;
typedef __attribute__((ext_vector_type(4))) float f32x4;
typedef __attribute__((ext_vector_type(4))) int i32x4;

#define BATCH 32
#define NCH   256
#define HW    56
#define NPIX  3136
#define XT_R  58

// Xt layout: [b][s8][hh58][ww58][fi32] bf16  (fi-chunk-major, halo built in)
#define XT_SLAB   (XT_R * XT_R * 32 * 2)            // 215,296 B per (b,s)
#define XT_BYTES  ((size_t)BATCH * 8 * XT_SLAB)     // 55,115,776
// Wm layout: [b][s8][tap9][fo256][fi32] bf16
#define WM_TAP    (256 * 32 * 2)                    // 16,384 B
#define WM_SLAB   (9 * WM_TAP)                      // 147,456 B per (b,s)
#define WM_B      (8 * WM_SLAB)                     // 1,179,648 B per b
#define WM_BYTES  ((size_t)BATCH * WM_B)            // 37,748,736
#define WS_NEEDED (XT_BYTES + WM_BYTES)             // ~92.9 MB (Xt first: B-stage overrun pads into Wm)

#define XT_BLKS   (BATCH * HW)                      // 1792
#define WM_BLKS   (BATCH * NCH)                     // 8192
#define HALO_BLKS (BATCH * 8)                       // 256
#define PREP_BLKS (XT_BLKS + WM_BLKS + HALO_BLKS)   // 10240

#define GLL16(g, l) __builtin_amdgcn_global_load_lds( \
    (const __attribute__((address_space(1))) void*)(g), \
    (__attribute__((address_space(3))) void*)(l), 16, 0, 0)

static __device__ __forceinline__ short f2bf(float f) {
    union { __hip_bfloat16 h; short s; } u;
    u.h = __float2bfloat16(f);
    return u.s;
}

// ---------------- fused prep: xt transpose + wm mask-multiply + halo zero ----------
// one launch, three disjoint block ranges; all outputs disjoint (halo=border, xt=interior)
__global__ __launch_bounds__(256) void prep_all(const float* __restrict__ x,
                                                const float* __restrict__ w,
                                                const float* __restrict__ m,
                                                char* __restrict__ xtb,
                                                char* __restrict__ wmb) {
    __shared__ __align__(16) char lds[28672];
    const int t = threadIdx.x;
    const int blk = blockIdx.x;

    if (blk < XT_BLKS) {
        // ---- xt: block = (b, h). Register-pack fi pairs -> swizzled [w][pair] LDS
        //      -> ds_read_b128 -> 16B coalesced global stores.
        unsigned* xl2 = (unsigned*)lds;          // [w56][p128] dw; col = p ^ ((w>>2)&7)<<2
        const int b = blk / HW, h = blk % HW;
        const float4* x4 = (const float4*)(x + (size_t)b * NCH * NPIX);
        const int rowb = h * 14;
#pragma unroll
        for (int it = 0; it < 7; ++it) {         // 1792 items = 128 pairs x 14 w-quads
            int c = it * 256 + t;
            int p = c / 14, j = c - p * 14;      // pair p (fi=2p,2p+1), w-quad j
            float4 a  = x4[(size_t)(2 * p)     * 784 + rowb + j];
            float4 bb = x4[(size_t)(2 * p + 1) * 784 + rowb + j];
            int col = p ^ ((j & 7) << 2);        // XOR-swizzle (w>>2)&7 into p bits 2-4
            unsigned d0 = ((unsigned)(unsigned short)f2bf(a.x)) | (((unsigned)(unsigned short)f2bf(bb.x)) << 16);
            unsigned d1 = ((unsigned)(unsigned short)f2bf(a.y)) | (((unsigned)(unsigned short)f2bf(bb.y)) << 16);
            unsigned d2 = ((unsigned)(unsigned short)f2bf(a.z)) | (((unsigned)(unsigned short)f2bf(bb.z)) << 16);
            unsigned d3 = ((unsigned)(unsigned short)f2bf(a.w)) | (((unsigned)(unsigned short)f2bf(bb.w)) << 16);
            unsigned* base = xl2 + j * 512 + col;   // (4j+k)*128 + col
            base[0]   = d0;
            base[128] = d1;
            base[256] = d2;
            base[384] = d3;
        }
        __syncthreads();
        char* ob = xtb + (size_t)(b * 8) * XT_SLAB + (h + 1) * 3712 + 64;
#pragma unroll
        for (int it = 0; it < 7; ++it) {         // 1792 chunks = 8s x 56ww x 4u, 16B each
            int c = it * 256 + t;
            int s = c / 224, rem = c - s * 224;
            int ww = rem >> 2, u = rem & 3;
            int col = (s * 16 + u * 4) ^ (((ww >> 2) & 7) << 2);
            i32x4 v = *(const i32x4*)(xl2 + ww * 128 + col);            // ds_read_b128
            *(i32x4*)(ob + (size_t)s * XT_SLAB + ww * 64 + u * 16) = v; // 16B store
        }
    } else if (blk < XT_BLKS + WM_BLKS) {
        // ---- wm: block = (b, fo). bf16(w*m) via swizzled [tap][fi] LDS -> b128 -> 16B stores
        short* prod2 = (short*)lds;              // byte = tap*512 + (fi*2 ^ ((tap&3)<<4))
        const int bk = blk - XT_BLKS;
        const int b = bk >> 8, fo = bk & 255;
        const float4* m4 = (const float4*)(m + ((size_t)(b * NCH + fo)) * 2304);
        const float4* w4 = (const float4*)(w + (size_t)fo * 2304);
#pragma unroll
        for (int i = 0; i < 3; ++i) {
            int idx = i * 256 + t;
            if (idx < 576) {
                float4 a = w4[idx], mm = m4[idx];
                int flat = idx * 4;
                float pr[4];
                pr[0] = a.x * mm.x; pr[1] = a.y * mm.y;
                pr[2] = a.z * mm.z; pr[3] = a.w * mm.w;
#pragma unroll
                for (int k2 = 0; k2 < 4; ++k2) {
                    int f2 = flat + k2;
                    int fi = f2 / 9, tap = f2 - fi * 9;
                    *(short*)((char*)prod2 + tap * 512 + ((fi * 2) ^ ((tap & 3) << 4))) = f2bf(pr[k2]);
                }
            }
        }
        __syncthreads();
        char* ob = wmb + (size_t)b * WM_B + fo * 64;
        for (int q = t; q < 288; q += 256) {     // 288 16B chunks: (s8, tap9, u4)
            int s = q / 36, r = q - s * 36;
            int tap = r >> 2, u = r & 3;
            i32x4 v = *(const i32x4*)((char*)prod2 + tap * 512 + ((s * 64 + u * 16) ^ ((tap & 3) << 4)));
            *(i32x4*)(ob + (size_t)s * WM_SLAB + tap * WM_TAP + u * 16) = v;
        }
    } else {
        // ---- halo zero: border of one (b,s) slab
        unsigned* p = (unsigned*)(xtb + (size_t)(blk - XT_BLKS - WM_BLKS) * XT_SLAB);
        for (int i = t; i < 928; i += 256) { p[i] = 0u; p[57 * 928 + i] = 0u; }
        for (int j = t; j < 896; j += 256) {
            int r = (j >> 4) + 1, c = j & 15;
            p[r * 928 + c] = 0u;
            p[r * 928 + 912 + c] = 0u;
        }
    }
}

// ---------------- main GEMM: block = 64 fo x 448 px (8 rows), K-loop = 8 fi-chunks -
// per fi-step: stage A(64x9x32) + B(10x58x32 halo), then 9 taps x 252 MFMA/wave
__global__ __launch_bounds__(256, 2) void gemm_dwa(const char* __restrict__ xtb,
                                                   const char* __restrict__ wmb,
                                                   const float* __restrict__ bias,
                                                   float* __restrict__ out) {
    __shared__ short Alds[2304 * 8];   // 36,864 B: [tap][fo64][fi32]
    __shared__ short Blds[2560 * 8];   // 40,960 B: [px 10x58][fi32] (+pad for uniform staging)

    const int tid = threadIdx.x, lane = tid & 63, wv = tid >> 6;
    const int ln = lane & 15, kg = lane >> 4;

    // XCD swizzle: pin each sample's working set to one XCD's L2 (perf heuristic only)
    const int blk = blockIdx.x;              // 896 = 8 xcd * 112
    const int xcd = blk & 7, slot = blk >> 3;
    const int b = xcd + 8 * (slot / 28);
    const int inner = slot % 28;
    const int ft = inner / 7, rt = inner % 7;
    const int fo0 = ft * 64, h0 = rt * 8;

    // per-lane B fragment pixel bases (halo-tile linear index, row stride 58)
    int pbase[7];
#pragma unroll
    for (int ni = 0; ni < 7; ++ni) {
        int p = wv * 112 + ni * 16 + ln;
        int hh = p / 56;
        pbase[ni] = hh * XT_R + (p - hh * 56);
    }

    const char* Ag = wmb + (size_t)b * WM_B + fo0 * 64;
    const char* Bg = xtb + (size_t)(b * 8) * XT_SLAB + h0 * 3712;

    f32x4 acc[4][7];
#pragma unroll
    for (int mi = 0; mi < 4; ++mi)
#pragma unroll
        for (int ni = 0; ni < 7; ++ni) acc[mi][ni] = (f32x4)0.0f;

    for (int s = 0; s < 8; ++s) {
        const char* ag = Ag + s * WM_SLAB;
        const char* bg = Bg + (size_t)s * XT_SLAB;

        __syncthreads();   // prior frag reads done
#pragma unroll
        for (int i = 0; i < 9; ++i) {          // A: 2304 chunks of 16B
            int c = i * 256 + tid;
            GLL16(ag + (c >> 8) * WM_TAP + (c & 255) * 16,
                  (char*)Alds + (i * 256 + wv * 64) * 16);
        }
#pragma unroll
        for (int i = 0; i < 10; ++i) {         // B: 2320 real + 240 pad chunks
            int c = i * 256 + tid;
            GLL16(bg + c * 16,
                  (char*)Blds + (i * 256 + wv * 64) * 16);
        }
        __syncthreads();   // staging drained

#pragma unroll
        for (int tap = 0; tap < 9; ++tap) {
            const int kh = tap / 3, kw = tap - kh * 3;
            const int shift = (kh * XT_R + kw) * 64;
            short8 af[4];
#pragma unroll
            for (int mi = 0; mi < 4; ++mi)
                af[mi] = *(const short8*)((const char*)Alds + tap * 4096 + (mi * 16 + ln) * 64 + kg * 16);
            short8 bf[7];
#pragma unroll
            for (int ni = 0; ni < 7; ++ni)
                bf[ni] = *(const short8*)((const char*)Blds + pbase[ni] * 64 + shift + kg * 16);
#pragma unroll
            for (int mi = 0; mi < 4; ++mi)
#pragma unroll
                for (int ni = 0; ni < 7; ++ni)
                    acc[mi][ni] = __builtin_amdgcn_mfma_f32_16x16x32_bf16(
                        af[mi], bf[ni], acc[mi][ni], 0, 0, 0);
        }
    }

    // epilogue: C row(fo) = (lane>>4)*4 + r, col(px) = lane&15 (round-2-verified)
#pragma unroll
    for (int mi = 0; mi < 4; ++mi) {
#pragma unroll
        for (int r = 0; r < 4; ++r) {
            const int row = fo0 + mi * 16 + kg * 4 + r;
            const float bv = bias[row];
            float* op = out + ((size_t)(b * NCH + row)) * NPIX + rt * 448 + wv * 112;
#pragma unroll
            for (int ni = 0; ni < 7; ++ni)
                op[ni * 16 + ln] = acc[mi][ni][r] + bv;
        }
    }
}

// ---------------- round-1 fp32 fallback (ws too small) -----------------------------
#define XS_W 60
#define XS_H 58
#define NGROUPS (NPIX / 4)
__global__ __launch_bounds__(256) void conv_dwa_fp32(
    const float* __restrict__ x, const float* __restrict__ m,
    const float* __restrict__ weight, const float* __restrict__ bias,
    float* __restrict__ out) {
    __shared__ float xs[XS_H * XS_W];
    const int tid = threadIdx.x, blk = blockIdx.x;
    const int b = blk >> 8, fo = blk & 255;
    const float* xb = x + (size_t)b * NCH * NPIX;
    const float* mb = m + ((size_t)b * NCH + fo) * (NCH * 9);
    const float* wb = weight + (size_t)fo * (NCH * 9);
    float acc[4][4];
#pragma unroll
    for (int g = 0; g < 4; ++g)
#pragma unroll
        for (int i = 0; i < 4; ++i) acc[g][i] = 0.0f;
    int rowbase[4];
#pragma unroll
    for (int g = 0; g < 4; ++g) {
        int p0 = (tid + g * 256) * 4;
        int gh = p0 / HW;
        rowbase[g] = gh * XS_W + (p0 - gh * HW);
    }
    for (int fi = 0; fi < NCH; ++fi) {
        const float* xp = xb + (size_t)fi * NPIX;
        __syncthreads();
        for (int idx = tid; idx < XS_H * 58; idx += 256) {
            int hh = idx / 58, ww = idx - hh * 58;
            int h = hh - 1, w = ww - 1;
            float v = 0.0f;
            if ((unsigned)h < HW && (unsigned)w < HW) v = xp[h * HW + w];
            xs[hh * XS_W + ww] = v;
        }
        float wm9[9];
#pragma unroll
        for (int j = 0; j < 9; ++j) wm9[j] = wb[fi * 9 + j] * mb[fi * 9 + j];
        __syncthreads();
#pragma unroll
        for (int g = 0; g < 4; ++g) {
            if (tid + g * 256 >= NGROUPS) break;
            const float* row0 = &xs[rowbase[g]];
#pragma unroll
            for (int kh = 0; kh < 3; ++kh) {
                const float* r = row0 + kh * XS_W;
                float s0 = r[0], s1 = r[1], s2 = r[2], s3 = r[3], s4 = r[4], s5 = r[5];
                const float w0 = wm9[3 * kh], w1 = wm9[3 * kh + 1], w2 = wm9[3 * kh + 2];
                acc[g][0] = fmaf(s2, w2, fmaf(s1, w1, fmaf(s0, w0, acc[g][0])));
                acc[g][1] = fmaf(s3, w2, fmaf(s2, w1, fmaf(s1, w0, acc[g][1])));
                acc[g][2] = fmaf(s4, w2, fmaf(s3, w1, fmaf(s2, w0, acc[g][2])));
                acc[g][3] = fmaf(s5, w2, fmaf(s4, w1, fmaf(s3, w0, acc[g][3])));
            }
        }
    }
    const float bv = bias[fo];
    float* ob = out + ((size_t)b * NCH + fo) * NPIX;
#pragma unroll
    for (int g = 0; g < 4; ++g) {
        int gi = tid + g * 256;
        if (gi >= NGROUPS) break;
        float4 v;
        v.x = acc[g][0] + bv; v.y = acc[g][1] + bv;
        v.z = acc[g][2] + bv; v.w = acc[g][3] + bv;
        *(float4*)(ob + gi * 4) = v;
    }
}

extern "C" void kernel_launch(void* const* d_in, const int* in_sizes, int n_in,
                              void* d_out, int out_size, void* d_ws, size_t ws_size,
                              hipStream_t stream) {
    const float* x      = (const float*)d_in[0];
    const float* m      = (const float*)d_in[1];
    const float* weight = (const float*)d_in[2];
    const float* bias   = (const float*)d_in[3];
    float* out          = (float*)d_out;

    if (ws_size < WS_NEEDED) {   // constant across calls -> graph-safe
        conv_dwa_fp32<<<dim3(BATCH * NCH), dim3(256), 0, stream>>>(x, m, weight, bias, out);
        return;
    }

    char* xtb = (char*)d_ws;            // Xt first: gemm B-stage pad overruns into Wm (in-bounds)
    char* wmb = xtb + XT_BYTES;

    prep_all<<<dim3(PREP_BLKS), dim3(256), 0, stream>>>(x, weight, m, xtb, wmb);
    gemm_dwa<<<dim3(896), dim3(256), 0, stream>>>(xtb, wmb, bias, out);
}